// Round 2
// baseline (9144.769 us; speedup 1.0000x reference)
//
#include <hip/hip_runtime.h>

// RNNSequenceEncoder: B=256, T=256, IN=128, H=1024
// Persistent kernel, PLAIN launch (round-1 cooperative launch silently failed:
// d_out stayed zero). 256 WGs = 16 row-blocks x 16 col-chunks; occupancy is
// >=1 block/CU so all 256 WGs are co-resident on the 256-CU chip -> custom
// counter barriers are starvation-free.
//   - W_rec slice (64x1024) in VGPRs as bf16 MFMA B-fragments (loaded once)
//   - per step: stage state tile (16x1024 bf16) to LDS (XOR swizzle),
//     32x mfma_16x16x32_bf16 (4 interleaved accumulators), fold next-step
//     ext = x_{t+1} @ W_in^T + b_in into the state write
//   - per-row-block barrier: PER-WAVE release-arrive / acquire-spin on a
//     device-memory counter (agent scope), __syncthreads after spin
//   - final: grid barrier, plop = state @ W_out^T + b_out, broadcast 256MB
// Scratch: d_ws if big enough, else d_out tail (fully overwritten at the end;
// grid-barrier spin exit is ">= target" so overwritten float bits still exit).

#define Bdim 256
#define Tdim 256
#define INdim 128
#define Hdim 1024

typedef __attribute__((ext_vector_type(8))) __bf16 bf16x8;
typedef __attribute__((ext_vector_type(4))) float f32x4;
typedef __attribute__((ext_vector_type(4))) int i32x4;

#define OUT_BYTES ((size_t)Bdim * Tdim * Hdim * 4)   /* 256 MB */
#define SBYTES ((size_t)Bdim * Hdim * 2)             /* one bf16 state buffer: 512 KB */
#define CNT_BYTES 8192
#define SCRATCH_BYTES (CNT_BYTES + 2 * SBYTES)

static __device__ __forceinline__ bf16x8 cvt8(f32x4 lo, f32x4 hi) {
  bf16x8 r;
  r[0] = (__bf16)lo[0]; r[1] = (__bf16)lo[1]; r[2] = (__bf16)lo[2]; r[3] = (__bf16)lo[3];
  r[4] = (__bf16)hi[0]; r[5] = (__bf16)hi[1]; r[6] = (__bf16)hi[2]; r[7] = (__bf16)hi[3];
  return r;
}

// Stage 16 rows x 1024 cols bf16 (32KB) global -> LDS, XOR swizzle on 16B
// chunks within each row: chunk ch lands at (ch ^ (row&7)).
static __device__ __forceinline__ void stage16(const __bf16* __restrict__ src,
                                               __bf16* sA, int tid) {
#pragma unroll
  for (int it = 0; it < 8; ++it) {
    int slot = it * 256 + tid;   // 2048 x 16B chunks
    int row = slot >> 7;
    int ch = slot & 127;
    i32x4 v = *(const i32x4*)(src + (size_t)row * Hdim + ch * 8);
    *(i32x4*)(sA + (size_t)row * Hdim + ((ch ^ (row & 7)) << 3)) = v;
  }
}

// A-fragment: lane holds A[row=lane&15][k0..k0+7], k0 = kk*32 + (lane>>4)*8.
// Same k-packing as the B-fragments, so any HW k-permutation cancels.
static __device__ __forceinline__ bf16x8 afrag(const __bf16* sA, int lane, int kk) {
  int row = lane & 15;
  int ch = kk * 4 + (lane >> 4);
  return *(const bf16x8*)(sA + (size_t)row * Hdim + ((ch ^ (row & 7)) << 3));
}

__global__ void zero_cnt(unsigned* c) { c[blockIdx.x * 256 + threadIdx.x] = 0u; }

__global__ void __launch_bounds__(256, 1)
rnn_fused(const float* __restrict__ x, const float* __restrict__ W_in,
          const float* __restrict__ b_in, const float* __restrict__ W_rec,
          const float* __restrict__ b_rec, const float* __restrict__ W_out,
          const float* __restrict__ b_out, float* __restrict__ out,
          char* __restrict__ scratch) {
  __shared__ __align__(16) __bf16 sA[16 * Hdim];  // 32 KB

  unsigned* counters = (unsigned*)scratch;
  __bf16* buf0 = (__bf16*)(scratch + CNT_BYTES);
  __bf16* buf1 = buf0 + (size_t)Bdim * Hdim;

  int wg = blockIdx.x;
  // Round-robin wg->XCD assumption: same (wg&7) = same XCD (perf only; the
  // agent-scope atomics keep it correct either way).
  int r = (wg & 7) + 8 * (wg >> 7);  // row block 0..15 (16 batch rows)
  int c = (wg >> 3) & 15;            // col chunk 0..15 (64 H cols)
  int tid = threadIdx.x;
  int lane = tid & 63;
  int w = tid >> 6;
  int kgrp = lane >> 4;
  int col = c * 64 + w * 16 + (lane & 15);  // H column owned by this lane (MFMA n)

  unsigned* cnt = counters + r * 64;   // 256B-spaced row-block counters
  unsigned* gcnt = counters + 16 * 64; // grid barrier counter

  // --- preload weights into registers ---
  bf16x8 wrec[32];  // W_rec row `col`, K=1024 -> 128 VGPRs
#pragma unroll
  for (int kk = 0; kk < 32; ++kk) {
    const float* p = W_rec + (size_t)col * Hdim + kk * 32 + kgrp * 8;
    wrec[kk] = cvt8(*(const f32x4*)p, *(const f32x4*)(p + 4));
  }
  bf16x8 win[4];    // W_in row `col`, K=128
#pragma unroll
  for (int kk = 0; kk < 4; ++kk) {
    const float* p = W_in + (size_t)col * INdim + kk * 32 + kgrp * 8;
    win[kk] = cvt8(*(const f32x4*)p, *(const f32x4*)(p + 4));
  }
  float b_rec_l = b_rec[col];
  float b_in_l = b_in[col];

  int xrow = 16 * r + (lane & 15);
  int xk0 = kgrp * 8;

  // --- phase 0: buf0 = ext_0 ---
  {
    f32x4 e = {0.f, 0.f, 0.f, 0.f};
#pragma unroll
    for (int kk = 0; kk < 4; ++kk) {
      const float* p = x + ((size_t)xrow * Tdim + 0) * INdim + kk * 32 + xk0;
      e = __builtin_amdgcn_mfma_f32_16x16x32_bf16(
          cvt8(*(const f32x4*)p, *(const f32x4*)(p + 4)), win[kk], e, 0, 0, 0);
    }
#pragma unroll
    for (int j = 0; j < 4; ++j)
      buf0[(size_t)(16 * r + kgrp * 4 + j) * Hdim + col] = (__bf16)(e[j] + b_in_l);
  }
  if (lane == 0) {
    __hip_atomic_fetch_add(cnt, 1u, __ATOMIC_RELEASE, __HIP_MEMORY_SCOPE_AGENT);
    while (__hip_atomic_load(cnt, __ATOMIC_ACQUIRE, __HIP_MEMORY_SCOPE_AGENT) < 64u)
      __builtin_amdgcn_s_sleep(2);
  }
  __syncthreads();

  // --- scan: 256 steps ---
  const __bf16* cur = buf0;
  __bf16* nxt = buf1;
  for (int t = 0; t < Tdim; ++t) {
    stage16(cur + (size_t)r * 16 * Hdim, sA, tid);
    f32x4 xlo[4], xhi[4];
    if (t + 1 < Tdim) {
#pragma unroll
      for (int kk = 0; kk < 4; ++kk) {
        const float* p = x + ((size_t)xrow * Tdim + (t + 1)) * INdim + kk * 32 + xk0;
        xlo[kk] = *(const f32x4*)p;
        xhi[kk] = *(const f32x4*)(p + 4);
      }
    }
    __syncthreads();
    f32x4 a0 = {0.f, 0.f, 0.f, 0.f}, a1 = a0, a2 = a0, a3 = a0;
#pragma unroll
    for (int kk = 0; kk < 32; kk += 4) {
      a0 = __builtin_amdgcn_mfma_f32_16x16x32_bf16(afrag(sA, lane, kk + 0), wrec[kk + 0], a0, 0, 0, 0);
      a1 = __builtin_amdgcn_mfma_f32_16x16x32_bf16(afrag(sA, lane, kk + 1), wrec[kk + 1], a1, 0, 0, 0);
      a2 = __builtin_amdgcn_mfma_f32_16x16x32_bf16(afrag(sA, lane, kk + 2), wrec[kk + 2], a2, 0, 0, 0);
      a3 = __builtin_amdgcn_mfma_f32_16x16x32_bf16(afrag(sA, lane, kk + 3), wrec[kk + 3], a3, 0, 0, 0);
    }
    f32x4 acc = (a0 + a1) + (a2 + a3);
    f32x4 e = {0.f, 0.f, 0.f, 0.f};
    if (t + 1 < Tdim) {
#pragma unroll
      for (int kk = 0; kk < 4; ++kk)
        e = __builtin_amdgcn_mfma_f32_16x16x32_bf16(cvt8(xlo[kk], xhi[kk]), win[kk], e, 0, 0, 0);
    }
    // C/D layout: col = lane&15, row = (lane>>4)*4 + j
#pragma unroll
    for (int j = 0; j < 4; ++j) {
      float s = acc[j] + b_rec_l;
      s = s > 0.f ? s : 0.f;
      float v = (t + 1 < Tdim) ? (s + e[j] + b_in_l) : s;
      nxt[(size_t)(16 * r + kgrp * 4 + j) * Hdim + col] = (__bf16)v;
    }
    // per-wave arrive + spin (each wave's release covers its own stores)
    if (lane == 0) {
      __hip_atomic_fetch_add(cnt, 1u, __ATOMIC_RELEASE, __HIP_MEMORY_SCOPE_AGENT);
      unsigned tgt = 64u * (unsigned)(t + 2);
      while (__hip_atomic_load(cnt, __ATOMIC_ACQUIRE, __HIP_MEMORY_SCOPE_AGENT) < tgt)
        __builtin_amdgcn_s_sleep(2);
    }
    __syncthreads();
    const __bf16* tmp = cur; cur = nxt; nxt = (__bf16*)tmp;
  }

  // --- output: plop = state_T @ W_out^T + b_out, broadcast over T ---
  // 256 swaps -> final state is in buf0
  stage16(buf0 + (size_t)r * 16 * Hdim, sA, tid);
  __syncthreads();
  // grid barrier: everyone staged its state before scratch may be overwritten
  // (out-tail mode). Spin exit is ">= 1024" so plop floats (big as uint32)
  // that later land on this line still release late spinners.
  if (lane == 0) {
    __hip_atomic_fetch_add(gcnt, 1u, __ATOMIC_RELEASE, __HIP_MEMORY_SCOPE_AGENT);
    while (__hip_atomic_load(gcnt, __ATOMIC_ACQUIRE, __HIP_MEMORY_SCOPE_AGENT) < 1024u)
      __builtin_amdgcn_s_sleep(2);
  }
  __syncthreads();

  f32x4 a0 = {0.f, 0.f, 0.f, 0.f}, a1 = a0;
#pragma unroll
  for (int kk = 0; kk < 32; kk += 2) {
    const float* p0 = W_out + (size_t)col * Hdim + (kk + 0) * 32 + kgrp * 8;
    const float* p1 = W_out + (size_t)col * Hdim + (kk + 1) * 32 + kgrp * 8;
    a0 = __builtin_amdgcn_mfma_f32_16x16x32_bf16(
        afrag(sA, lane, kk + 0), cvt8(*(const f32x4*)p0, *(const f32x4*)(p0 + 4)), a0, 0, 0, 0);
    a1 = __builtin_amdgcn_mfma_f32_16x16x32_bf16(
        afrag(sA, lane, kk + 1), cvt8(*(const f32x4*)p1, *(const f32x4*)(p1 + 4)), a1, 0, 0, 0);
  }
  f32x4 acc = a0 + a1;
  float bo = b_out[col];
  __syncthreads();  // afrag reads done before sA reuse
  float* sP = (float*)sA;  // 16 x 64 plop tile
#pragma unroll
  for (int j = 0; j < 4; ++j)
    sP[(kgrp * 4 + j) * 64 + w * 16 + (lane & 15)] = acc[j] + bo;
  __syncthreads();

  int h16 = tid & 15, tloc = tid >> 4;
  for (int b = 0; b < 16; ++b) {
    f32x4 v = *(const f32x4*)(sP + b * 64 + h16 * 4);
#pragma unroll
    for (int tb = 0; tb < 16; ++tb) {
      int t = tb * 16 + tloc;
      *(f32x4*)(out + ((size_t)(16 * r + b) * Tdim + t) * Hdim + 64 * c + h16 * 4) = v;
    }
  }
}

extern "C" void kernel_launch(void* const* d_in, const int* in_sizes, int n_in,
                              void* d_out, int out_size, void* d_ws, size_t ws_size,
                              hipStream_t stream) {
  const float* x = (const float*)d_in[0];
  const float* W_in = (const float*)d_in[1];
  const float* b_in = (const float*)d_in[2];
  const float* W_rec = (const float*)d_in[3];
  const float* b_rec = (const float*)d_in[4];
  const float* W_out = (const float*)d_in[5];
  const float* b_out = (const float*)d_in[6];
  float* out = (float*)d_out;
  (void)in_sizes; (void)n_in; (void)out_size;

  char* scratch = (ws_size >= SCRATCH_BYTES)
                      ? (char*)d_ws
                      : ((char*)d_out + OUT_BYTES - SCRATCH_BYTES);

  // zero barrier counters with a tiny kernel (no runtime APIs in the capture)
  zero_cnt<<<dim3(CNT_BYTES / 1024), dim3(256), 0, stream>>>((unsigned*)scratch);
  rnn_fused<<<dim3(256), dim3(256), 0, stream>>>(x, W_in, b_in, W_rec, b_rec,
                                                 W_out, b_out, out, scratch);
}

// Round 3
// 3181.653 us; speedup vs baseline: 2.8742x; 2.8742x over previous
//
#include <hip/hip_runtime.h>

// RNNSequenceEncoder: B=256, T=256, IN=128, H=1024
// Round-3: barrier redesign. Round-2 was 36us/step, all of it the 64-arrival
// single-cacheline agent-scope atomic_fetch_add barrier (RMWs serialize at the
// coherence point ~500ns each). Now:
//   - 128 WGs x 512 threads (8 waves): row-block r (16 batch rows) split over
//     8 WGs x 128 cols. 1 WG/CU, XCD-colocated by round-robin swizzle.
//   - distributed-flag barrier: ONE relaxed atomic store per WG per step to
//     its own 128B-spaced flag; release-fence (one buffer_wbl2) before it;
//     8 pollers do relaxed atomic loads on distinct lines; one acquire-fence
//     (buffer_inv) after exit. No RMWs, no per-poll invalidate.
//   - everything else as round-2: W_rec slice in VGPRs, state tile staged to
//     LDS with XOR swizzle, ext folded into state write, broadcast epilogue.

#define Bdim 256
#define Tdim 256
#define INdim 128
#define Hdim 1024

typedef __attribute__((ext_vector_type(8))) __bf16 bf16x8;
typedef __attribute__((ext_vector_type(4))) float f32x4;
typedef __attribute__((ext_vector_type(4))) int i32x4;

#define OUT_BYTES ((size_t)Bdim * Tdim * Hdim * 4)   /* 256 MB */
#define SBYTES ((size_t)Bdim * Hdim * 2)             /* one bf16 state buffer: 512 KB */
#define CNT_BYTES 32768
#define SCRATCH_BYTES (CNT_BYTES + 2 * SBYTES)

static __device__ __forceinline__ bf16x8 cvt8(f32x4 lo, f32x4 hi) {
  bf16x8 r;
  r[0] = (__bf16)lo[0]; r[1] = (__bf16)lo[1]; r[2] = (__bf16)lo[2]; r[3] = (__bf16)lo[3];
  r[4] = (__bf16)hi[0]; r[5] = (__bf16)hi[1]; r[6] = (__bf16)hi[2]; r[7] = (__bf16)hi[3];
  return r;
}

// Stage 16 rows x 1024 cols bf16 (32KB) global -> LDS, XOR swizzle on 16B
// chunks within each row: chunk ch lands at (ch ^ (row&7)). 512 threads.
static __device__ __forceinline__ void stage16(const __bf16* __restrict__ src,
                                               __bf16* sA, int tid) {
#pragma unroll
  for (int it = 0; it < 4; ++it) {
    int slot = it * 512 + tid;   // 2048 x 16B chunks
    int row = slot >> 7;
    int ch = slot & 127;
    i32x4 v = *(const i32x4*)(src + (size_t)row * Hdim + ch * 8);
    *(i32x4*)(sA + (size_t)row * Hdim + ((ch ^ (row & 7)) << 3)) = v;
  }
}

// A-fragment: lane holds A[row=lane&15][k0..k0+7], k0 = kk*32 + (lane>>4)*8,
// through the same XOR swizzle. A and B use identical K-packing so any HW
// K-permutation cancels.
static __device__ __forceinline__ bf16x8 afrag(const __bf16* sA, int lane, int kk) {
  int row = lane & 15;
  int ch = kk * 4 + (lane >> 4);
  return *(const bf16x8*)(sA + (size_t)row * Hdim + ((ch ^ (row & 7)) << 3));
}

__global__ void zero_cnt(unsigned* c) { c[blockIdx.x * 256 + threadIdx.x] = 0u; }

__global__ void __launch_bounds__(512, 1)
rnn_fused(const float* __restrict__ x, const float* __restrict__ W_in,
          const float* __restrict__ b_in, const float* __restrict__ W_rec,
          const float* __restrict__ b_rec, const float* __restrict__ W_out,
          const float* __restrict__ b_out, float* __restrict__ out,
          char* __restrict__ scratch) {
  __shared__ __align__(16) __bf16 sA[16 * Hdim];  // 32 KB

  unsigned* counters = (unsigned*)scratch;
  __bf16* buf0 = (__bf16*)(scratch + CNT_BYTES);
  __bf16* buf1 = buf0 + (size_t)Bdim * Hdim;

  int wg = blockIdx.x;               // 0..127
  int idx = wg >> 3;                 // 0..15
  int r = (wg & 7) + 8 * (idx & 1);  // row block 0..15; its 8 WGs share wg&7
  int c = idx >> 1;                  // col chunk 0..7 (128 H cols)
  int tid = threadIdx.x;
  int lane = tid & 63;
  int ww = tid >> 6;                 // wave 0..7
  int kgrp = lane >> 4;
  int col = c * 128 + ww * 16 + (lane & 15);  // H column (MFMA n = lane&15)

  // flags: row-block r's 8 flags at counters[(r*8+i)*32], 128B apart
  unsigned* rbf = counters + (size_t)r * 8 * 32;
  unsigned* myflag = rbf + (size_t)c * 32;
  unsigned* gflags = counters + 4096;  // 128 one-shot flags, 64B apart

  // --- preload weights into registers ---
  bf16x8 wrec[32];  // W_rec row `col`, K=1024 -> 128 VGPRs
#pragma unroll
  for (int kk = 0; kk < 32; ++kk) {
    const float* p = W_rec + (size_t)col * Hdim + kk * 32 + kgrp * 8;
    wrec[kk] = cvt8(*(const f32x4*)p, *(const f32x4*)(p + 4));
  }
  bf16x8 win[4];    // W_in row `col`, K=128
#pragma unroll
  for (int kk = 0; kk < 4; ++kk) {
    const float* p = W_in + (size_t)col * INdim + kk * 32 + kgrp * 8;
    win[kk] = cvt8(*(const f32x4*)p, *(const f32x4*)(p + 4));
  }
  float b_rec_l = b_rec[col];
  float b_in_l = b_in[col];

  int xrow = 16 * r + (lane & 15);
  int xk0 = kgrp * 8;

  // --- phase 0: buf0 = version 1 = ext_0 ---
  {
    f32x4 e = {0.f, 0.f, 0.f, 0.f};
#pragma unroll
    for (int kk = 0; kk < 4; ++kk) {
      const float* p = x + ((size_t)xrow * Tdim + 0) * INdim + kk * 32 + xk0;
      e = __builtin_amdgcn_mfma_f32_16x16x32_bf16(
          cvt8(*(const f32x4*)p, *(const f32x4*)(p + 4)), win[kk], e, 0, 0, 0);
    }
#pragma unroll
    for (int j = 0; j < 4; ++j)
      buf0[(size_t)(16 * r + kgrp * 4 + j) * Hdim + col] = (__bf16)(e[j] + b_in_l);
  }
  // barrier: version 1 visible
  __syncthreads();
  if (tid == 0) {
    __builtin_amdgcn_fence(__ATOMIC_RELEASE, "agent");
    __hip_atomic_store(myflag, 1u, __ATOMIC_RELAXED, __HIP_MEMORY_SCOPE_AGENT);
  }
  if (tid < 8) {
    unsigned* f = rbf + tid * 32;
    while (__hip_atomic_load(f, __ATOMIC_RELAXED, __HIP_MEMORY_SCOPE_AGENT) < 1u)
      __builtin_amdgcn_s_sleep(2);
  }
  __syncthreads();
  __builtin_amdgcn_fence(__ATOMIC_ACQUIRE, "agent");

  // --- scan: 256 steps; version t+1 in buf[t&1] ---
  const __bf16* cur = buf0;
  __bf16* nxt = buf1;
  for (int t = 0; t < Tdim; ++t) {
    stage16(cur + (size_t)r * 16 * Hdim, sA, tid);
    f32x4 xlo[4], xhi[4];
    if (t + 1 < Tdim) {
#pragma unroll
      for (int kk = 0; kk < 4; ++kk) {
        const float* p = x + ((size_t)xrow * Tdim + (t + 1)) * INdim + kk * 32 + xk0;
        xlo[kk] = *(const f32x4*)p;
        xhi[kk] = *(const f32x4*)(p + 4);
      }
    }
    __syncthreads();
    f32x4 a0 = {0.f, 0.f, 0.f, 0.f}, a1 = a0, a2 = a0, a3 = a0;
#pragma unroll
    for (int kk = 0; kk < 32; kk += 4) {
      a0 = __builtin_amdgcn_mfma_f32_16x16x32_bf16(afrag(sA, lane, kk + 0), wrec[kk + 0], a0, 0, 0, 0);
      a1 = __builtin_amdgcn_mfma_f32_16x16x32_bf16(afrag(sA, lane, kk + 1), wrec[kk + 1], a1, 0, 0, 0);
      a2 = __builtin_amdgcn_mfma_f32_16x16x32_bf16(afrag(sA, lane, kk + 2), wrec[kk + 2], a2, 0, 0, 0);
      a3 = __builtin_amdgcn_mfma_f32_16x16x32_bf16(afrag(sA, lane, kk + 3), wrec[kk + 3], a3, 0, 0, 0);
    }
    f32x4 acc = (a0 + a1) + (a2 + a3);
    f32x4 e = {0.f, 0.f, 0.f, 0.f};
    if (t + 1 < Tdim) {
#pragma unroll
      for (int kk = 0; kk < 4; ++kk)
        e = __builtin_amdgcn_mfma_f32_16x16x32_bf16(cvt8(xlo[kk], xhi[kk]), win[kk], e, 0, 0, 0);
    }
    // C/D layout: col = lane&15, row = (lane>>4)*4 + j
#pragma unroll
    for (int j = 0; j < 4; ++j) {
      float s = acc[j] + b_rec_l;
      s = s > 0.f ? s : 0.f;
      float v = (t + 1 < Tdim) ? (s + e[j] + b_in_l) : s;
      nxt[(size_t)(16 * r + kgrp * 4 + j) * Hdim + col] = (__bf16)v;
    }
    // barrier: version t+2 visible. Writer of v+1 polls all >= v, which also
    // guarantees nobody still reads v-1 (2-deep double buffer is safe).
    unsigned tgt = (unsigned)(t + 2);
    __syncthreads();
    if (tid == 0) {
      __builtin_amdgcn_fence(__ATOMIC_RELEASE, "agent");
      __hip_atomic_store(myflag, tgt, __ATOMIC_RELAXED, __HIP_MEMORY_SCOPE_AGENT);
    }
    if (tid < 8) {
      unsigned* f = rbf + tid * 32;
      while (__hip_atomic_load(f, __ATOMIC_RELAXED, __HIP_MEMORY_SCOPE_AGENT) < tgt)
        __builtin_amdgcn_s_sleep(2);
    }
    __syncthreads();
    __builtin_amdgcn_fence(__ATOMIC_ACQUIRE, "agent");
    const __bf16* tmp = cur; cur = nxt; nxt = (__bf16*)tmp;
  }

  // --- output: plop = state_257 @ W_out^T + b_out, broadcast over T ---
  // version 257 is in buf0 (cur == buf0 after 256 swaps)
  stage16(buf0 + (size_t)r * 16 * Hdim, sA, tid);
  __syncthreads();
  // one-shot grid barrier (tail-scratch safety: nobody writes output over the
  // scratch region until everyone staged its state into LDS)
  if (tid == 0) {
    __builtin_amdgcn_fence(__ATOMIC_RELEASE, "agent");
    __hip_atomic_store(gflags + (size_t)wg * 16, 1u, __ATOMIC_RELAXED,
                       __HIP_MEMORY_SCOPE_AGENT);
  }
  if (tid < 128) {
    unsigned* f = gflags + (size_t)tid * 16;
    while (__hip_atomic_load(f, __ATOMIC_RELAXED, __HIP_MEMORY_SCOPE_AGENT) < 1u)
      __builtin_amdgcn_s_sleep(2);
  }
  __syncthreads();

  f32x4 a0 = {0.f, 0.f, 0.f, 0.f}, a1 = a0;
#pragma unroll
  for (int kk = 0; kk < 32; kk += 2) {
    const float* p0 = W_out + (size_t)col * Hdim + (kk + 0) * 32 + kgrp * 8;
    const float* p1 = W_out + (size_t)col * Hdim + (kk + 1) * 32 + kgrp * 8;
    a0 = __builtin_amdgcn_mfma_f32_16x16x32_bf16(
        afrag(sA, lane, kk + 0), cvt8(*(const f32x4*)p0, *(const f32x4*)(p0 + 4)), a0, 0, 0, 0);
    a1 = __builtin_amdgcn_mfma_f32_16x16x32_bf16(
        afrag(sA, lane, kk + 1), cvt8(*(const f32x4*)p1, *(const f32x4*)(p1 + 4)), a1, 0, 0, 0);
  }
  f32x4 acc = a0 + a1;
  float bo = b_out[col];
  __syncthreads();  // afrag reads done before sA reuse
  float* sP = (float*)sA;  // 16 x 128 plop tile (f32, 8KB)
#pragma unroll
  for (int j = 0; j < 4; ++j)
    sP[(kgrp * 4 + j) * 128 + ww * 16 + (lane & 15)] = acc[j] + bo;
  __syncthreads();

  int h32 = tid & 31, tloc = tid >> 5;  // 32 f32x4-cols, 16 t-phases
  for (int b = 0; b < 16; ++b) {
    f32x4 v = *(const f32x4*)(sP + b * 128 + h32 * 4);
#pragma unroll
    for (int tb = 0; tb < 16; ++tb) {
      int t = tb * 16 + tloc;
      *(f32x4*)(out + ((size_t)(16 * r + b) * Tdim + t) * Hdim + 128 * c + h32 * 4) = v;
    }
  }
}

extern "C" void kernel_launch(void* const* d_in, const int* in_sizes, int n_in,
                              void* d_out, int out_size, void* d_ws, size_t ws_size,
                              hipStream_t stream) {
  const float* x = (const float*)d_in[0];
  const float* W_in = (const float*)d_in[1];
  const float* b_in = (const float*)d_in[2];
  const float* W_rec = (const float*)d_in[3];
  const float* b_rec = (const float*)d_in[4];
  const float* W_out = (const float*)d_in[5];
  const float* b_out = (const float*)d_in[6];
  float* out = (float*)d_out;
  (void)in_sizes; (void)n_in; (void)out_size;

  char* scratch = (ws_size >= SCRATCH_BYTES)
                      ? (char*)d_ws
                      : ((char*)d_out + OUT_BYTES - SCRATCH_BYTES);

  zero_cnt<<<dim3(CNT_BYTES / 1024), dim3(256), 0, stream>>>((unsigned*)scratch);
  rnn_fused<<<dim3(128), dim3(512), 0, stream>>>(x, W_in, b_in, W_rec, b_rec,
                                                 W_out, b_out, out, scratch);
}

// Round 4
// 1257.515 us; speedup vs baseline: 7.2721x; 2.5301x over previous
//
#include <hip/hip_runtime.h>

// RNNSequenceEncoder: B=256, T=256, IN=128, H=1024
// Round-4: fence-free device-coherent exchange. Round-3 paid per-step
// agent-scope fences (release = buffer_wbl2, acquire = buffer_inv -> full L2
// writeback+invalidate per WG per step, ~12us/step). Now ALL cross-WG data
// (state, flags) moves via sc0|sc1 (device-coherent, L1/L2-bypass) inline-asm
// loads/stores to the coherence point; no fences at all, L2 stays warm for
// x/weights, and correctness is independent of wg->XCD mapping.
//   - 128 WGs x 512 threads: row-block r (16 batch rows) x 8 WGs (128 cols).
//   - W_rec slice in VGPRs; state tile staged to LDS (XOR swizzle); ext
//     folded into state write; distributed per-WG epoch flags.

#define Bdim 256
#define Tdim 256
#define INdim 128
#define Hdim 1024

typedef __attribute__((ext_vector_type(8))) __bf16 bf16x8;
typedef __attribute__((ext_vector_type(4))) float f32x4;
typedef __attribute__((ext_vector_type(4))) int i32x4;

#define OUT_BYTES ((size_t)Bdim * Tdim * Hdim * 4)   /* 256 MB */
#define SBYTES ((size_t)Bdim * Hdim * 2)             /* one bf16 state buffer: 512 KB */
#define CNT_BYTES 32768
#define SCRATCH_BYTES (CNT_BYTES + 2 * SBYTES)

// --- device-coherent memory ops (bypass L1+L2, visible device-wide, no fence) ---
static __device__ __forceinline__ void st_b16_c(void* p, unsigned v) {
  asm volatile("global_store_short %0, %1, off sc0 sc1" :: "v"(p), "v"(v) : "memory");
}
static __device__ __forceinline__ void st_b32_c(void* p, unsigned v) {
  asm volatile("global_store_dword %0, %1, off sc0 sc1" :: "v"(p), "v"(v) : "memory");
}
static __device__ __forceinline__ unsigned ld_b32_c(const void* p) {
  unsigned v;
  asm volatile("global_load_dword %0, %1, off sc0 sc1\n\ts_waitcnt vmcnt(0)"
               : "=v"(v) : "v"(p) : "memory");
  return v;
}
static __device__ __forceinline__ i32x4 ld_b128_c(const void* p) {
  i32x4 v;
  asm volatile("global_load_dwordx4 %0, %1, off sc0 sc1" : "=v"(v) : "v"(p) : "memory");
  return v;
}
static __device__ __forceinline__ void wait_vm0() {
  asm volatile("s_waitcnt vmcnt(0)" ::: "memory");
}

static __device__ __forceinline__ bf16x8 cvt8(f32x4 lo, f32x4 hi) {
  bf16x8 r;
  r[0] = (__bf16)lo[0]; r[1] = (__bf16)lo[1]; r[2] = (__bf16)lo[2]; r[3] = (__bf16)lo[3];
  r[4] = (__bf16)hi[0]; r[5] = (__bf16)hi[1]; r[6] = (__bf16)hi[2]; r[7] = (__bf16)hi[3];
  return r;
}

// Stage 16 rows x 1024 cols bf16 (32KB) coherence-point -> LDS, XOR swizzle on
// 16B chunks within each row (chunk ch lands at ch ^ (row&7)). 512 threads.
// 4 loads issued back-to-back (pipelined), one vmcnt(0), then LDS writes.
static __device__ __forceinline__ void stage16c(const __bf16* __restrict__ src,
                                                __bf16* sA, int tid) {
  i32x4 v0, v1, v2, v3;
  int r0 = (tid + 0) >> 7, c0 = (tid + 0) & 127;
  int r1 = (tid + 512) >> 7, c1 = (tid + 512) & 127;
  int r2 = (tid + 1024) >> 7, c2 = (tid + 1024) & 127;
  int r3 = (tid + 1536) >> 7, c3 = (tid + 1536) & 127;
  v0 = ld_b128_c(src + (size_t)r0 * Hdim + c0 * 8);
  v1 = ld_b128_c(src + (size_t)r1 * Hdim + c1 * 8);
  v2 = ld_b128_c(src + (size_t)r2 * Hdim + c2 * 8);
  v3 = ld_b128_c(src + (size_t)r3 * Hdim + c3 * 8);
  wait_vm0();
  *(i32x4*)(sA + (size_t)r0 * Hdim + ((c0 ^ (r0 & 7)) << 3)) = v0;
  *(i32x4*)(sA + (size_t)r1 * Hdim + ((c1 ^ (r1 & 7)) << 3)) = v1;
  *(i32x4*)(sA + (size_t)r2 * Hdim + ((c2 ^ (r2 & 7)) << 3)) = v2;
  *(i32x4*)(sA + (size_t)r3 * Hdim + ((c3 ^ (r3 & 7)) << 3)) = v3;
}

// A-fragment: lane holds A[row=lane&15][k0..k0+7], k0 = kk*32 + (lane>>4)*8,
// through the same XOR swizzle. A and B use identical K-packing so any HW
// K-permutation cancels.
static __device__ __forceinline__ bf16x8 afrag(const __bf16* sA, int lane, int kk) {
  int row = lane & 15;
  int ch = kk * 4 + (lane >> 4);
  return *(const bf16x8*)(sA + (size_t)row * Hdim + ((ch ^ (row & 7)) << 3));
}

__global__ void zero_cnt(unsigned* c) { c[blockIdx.x * 256 + threadIdx.x] = 0u; }

__global__ void __launch_bounds__(512, 1)
rnn_fused(const float* __restrict__ x, const float* __restrict__ W_in,
          const float* __restrict__ b_in, const float* __restrict__ W_rec,
          const float* __restrict__ b_rec, const float* __restrict__ W_out,
          const float* __restrict__ b_out, float* __restrict__ out,
          char* __restrict__ scratch) {
  __shared__ __align__(16) __bf16 sA[16 * Hdim];  // 32 KB

  unsigned* counters = (unsigned*)scratch;
  __bf16* buf0 = (__bf16*)(scratch + CNT_BYTES);
  __bf16* buf1 = buf0 + (size_t)Bdim * Hdim;

  int wg = blockIdx.x;               // 0..127
  int idx = wg >> 3;                 // 0..15
  int r = (wg & 7) + 8 * (idx & 1);  // row block 0..15; its 8 WGs share wg&7
  int c = idx >> 1;                  // col chunk 0..7 (128 H cols)
  int tid = threadIdx.x;
  int lane = tid & 63;
  int ww = tid >> 6;                 // wave 0..7
  int kgrp = lane >> 4;
  int col = c * 128 + ww * 16 + (lane & 15);  // H column (MFMA n = lane&15)

  // flags: row-block r's 8 flags at counters[(r*8+i)*32], 128B apart
  unsigned* rbf = counters + (size_t)r * 8 * 32;
  unsigned* myflag = rbf + (size_t)c * 32;
  unsigned* gflags = counters + 4096;  // 128 one-shot flags, 64B apart

  // --- preload weights into registers (normal cached loads; read-only) ---
  bf16x8 wrec[32];  // W_rec row `col`, K=1024 -> 128 VGPRs
#pragma unroll
  for (int kk = 0; kk < 32; ++kk) {
    const float* p = W_rec + (size_t)col * Hdim + kk * 32 + kgrp * 8;
    wrec[kk] = cvt8(*(const f32x4*)p, *(const f32x4*)(p + 4));
  }
  bf16x8 win[4];    // W_in row `col`, K=128
#pragma unroll
  for (int kk = 0; kk < 4; ++kk) {
    const float* p = W_in + (size_t)col * INdim + kk * 32 + kgrp * 8;
    win[kk] = cvt8(*(const f32x4*)p, *(const f32x4*)(p + 4));
  }
  float b_rec_l = b_rec[col];
  float b_in_l = b_in[col];

  int xrow = 16 * r + (lane & 15);
  int xk0 = kgrp * 8;

  // --- phase 0: buf0 = version 1 = ext_0 (coherent stores) ---
  {
    f32x4 e = {0.f, 0.f, 0.f, 0.f};
#pragma unroll
    for (int kk = 0; kk < 4; ++kk) {
      const float* p = x + ((size_t)xrow * Tdim + 0) * INdim + kk * 32 + xk0;
      e = __builtin_amdgcn_mfma_f32_16x16x32_bf16(
          cvt8(*(const f32x4*)p, *(const f32x4*)(p + 4)), win[kk], e, 0, 0, 0);
    }
#pragma unroll
    for (int j = 0; j < 4; ++j) {
      __bf16 b = (__bf16)(e[j] + b_in_l);
      st_b16_c(buf0 + (size_t)(16 * r + kgrp * 4 + j) * Hdim + col,
               (unsigned)__builtin_bit_cast(unsigned short, b));
    }
  }
  wait_vm0();
  __syncthreads();
  if (tid == 0) st_b32_c(myflag, 1u);
  if (tid < 8) {
    unsigned* f = rbf + tid * 32;
    while (ld_b32_c(f) < 1u) __builtin_amdgcn_s_sleep(1);
  }
  __syncthreads();

  // --- scan: 256 steps; version t+1 in buf[t&1] ---
  const __bf16* cur = buf0;
  __bf16* nxt = buf1;
  for (int t = 0; t < Tdim; ++t) {
    stage16c(cur + (size_t)r * 16 * Hdim, sA, tid);
    f32x4 xlo[4], xhi[4];
    if (t + 1 < Tdim) {
#pragma unroll
      for (int kk = 0; kk < 4; ++kk) {
        const float* p = x + ((size_t)xrow * Tdim + (t + 1)) * INdim + kk * 32 + xk0;
        xlo[kk] = *(const f32x4*)p;
        xhi[kk] = *(const f32x4*)(p + 4);
      }
    }
    __syncthreads();
    f32x4 a0 = {0.f, 0.f, 0.f, 0.f}, a1 = a0, a2 = a0, a3 = a0;
#pragma unroll
    for (int kk = 0; kk < 32; kk += 4) {
      a0 = __builtin_amdgcn_mfma_f32_16x16x32_bf16(afrag(sA, lane, kk + 0), wrec[kk + 0], a0, 0, 0, 0);
      a1 = __builtin_amdgcn_mfma_f32_16x16x32_bf16(afrag(sA, lane, kk + 1), wrec[kk + 1], a1, 0, 0, 0);
      a2 = __builtin_amdgcn_mfma_f32_16x16x32_bf16(afrag(sA, lane, kk + 2), wrec[kk + 2], a2, 0, 0, 0);
      a3 = __builtin_amdgcn_mfma_f32_16x16x32_bf16(afrag(sA, lane, kk + 3), wrec[kk + 3], a3, 0, 0, 0);
    }
    f32x4 acc = (a0 + a1) + (a2 + a3);
    f32x4 e = {0.f, 0.f, 0.f, 0.f};
    if (t + 1 < Tdim) {
#pragma unroll
      for (int kk = 0; kk < 4; ++kk)
        e = __builtin_amdgcn_mfma_f32_16x16x32_bf16(cvt8(xlo[kk], xhi[kk]), win[kk], e, 0, 0, 0);
    }
    // C/D layout: col = lane&15, row = (lane>>4)*4 + j; coherent 2B stores
#pragma unroll
    for (int j = 0; j < 4; ++j) {
      float s = acc[j] + b_rec_l;
      s = s > 0.f ? s : 0.f;
      float v = (t + 1 < Tdim) ? (s + e[j] + b_in_l) : s;
      __bf16 b = (__bf16)v;
      st_b16_c(nxt + (size_t)(16 * r + kgrp * 4 + j) * Hdim + col,
               (unsigned)__builtin_bit_cast(unsigned short, b));
    }
    // publish version t+2: own stores ack'd -> barrier -> flag -> poll peers.
    // Poll exit at >= t+2 also proves nobody still reads version t+1's buffer
    // (their reads of it finished before they arrived), so 2-buffer is safe.
    unsigned tgt = (unsigned)(t + 2);
    wait_vm0();
    __syncthreads();
    if (tid == 0) st_b32_c(myflag, tgt);
    if (tid < 8) {
      unsigned* f = rbf + tid * 32;
      while (ld_b32_c(f) < tgt) __builtin_amdgcn_s_sleep(1);
    }
    __syncthreads();
    const __bf16* tmp = cur; cur = nxt; nxt = (__bf16*)tmp;
  }

  // --- output: plop = state_257 @ W_out^T + b_out, broadcast over T ---
  // version 257 is in buf0 (cur == buf0 after 256 swaps)
  stage16c(buf0 + (size_t)r * 16 * Hdim, sA, tid);
  __syncthreads();
  // one-shot grid barrier (tail-scratch safety: nobody writes output over the
  // scratch region until everyone staged its state into LDS)
  if (tid == 0) st_b32_c(gflags + (size_t)wg * 16, 1u);
  if (tid < 128) {
    unsigned* f = gflags + (size_t)tid * 16;
    while (ld_b32_c(f) < 1u) __builtin_amdgcn_s_sleep(1);
  }
  __syncthreads();

  f32x4 a0 = {0.f, 0.f, 0.f, 0.f}, a1 = a0;
#pragma unroll
  for (int kk = 0; kk < 32; kk += 2) {
    const float* p0 = W_out + (size_t)col * Hdim + (kk + 0) * 32 + kgrp * 8;
    const float* p1 = W_out + (size_t)col * Hdim + (kk + 1) * 32 + kgrp * 8;
    a0 = __builtin_amdgcn_mfma_f32_16x16x32_bf16(
        afrag(sA, lane, kk + 0), cvt8(*(const f32x4*)p0, *(const f32x4*)(p0 + 4)), a0, 0, 0, 0);
    a1 = __builtin_amdgcn_mfma_f32_16x16x32_bf16(
        afrag(sA, lane, kk + 1), cvt8(*(const f32x4*)p1, *(const f32x4*)(p1 + 4)), a1, 0, 0, 0);
  }
  f32x4 acc = a0 + a1;
  float bo = b_out[col];
  __syncthreads();  // afrag reads done before sA reuse
  float* sP = (float*)sA;  // 16 x 128 plop tile (f32, 8KB)
#pragma unroll
  for (int j = 0; j < 4; ++j)
    sP[(kgrp * 4 + j) * 128 + ww * 16 + (lane & 15)] = acc[j] + bo;
  __syncthreads();

  int h32 = tid & 31, tloc = tid >> 5;  // 32 f32x4-cols, 16 t-phases
  for (int b = 0; b < 16; ++b) {
    f32x4 v = *(const f32x4*)(sP + b * 128 + h32 * 4);
#pragma unroll
    for (int tb = 0; tb < 16; ++tb) {
      int t = tb * 16 + tloc;
      *(f32x4*)(out + ((size_t)(16 * r + b) * Tdim + t) * Hdim + 128 * c + h32 * 4) = v;
    }
  }
}

extern "C" void kernel_launch(void* const* d_in, const int* in_sizes, int n_in,
                              void* d_out, int out_size, void* d_ws, size_t ws_size,
                              hipStream_t stream) {
  const float* x = (const float*)d_in[0];
  const float* W_in = (const float*)d_in[1];
  const float* b_in = (const float*)d_in[2];
  const float* W_rec = (const float*)d_in[3];
  const float* b_rec = (const float*)d_in[4];
  const float* W_out = (const float*)d_in[5];
  const float* b_out = (const float*)d_in[6];
  float* out = (float*)d_out;
  (void)in_sizes; (void)n_in; (void)out_size;

  char* scratch = (ws_size >= SCRATCH_BYTES)
                      ? (char*)d_ws
                      : ((char*)d_out + OUT_BYTES - SCRATCH_BYTES);

  zero_cnt<<<dim3(CNT_BYTES / 1024), dim3(256), 0, stream>>>((unsigned*)scratch);
  rnn_fused<<<dim3(128), dim3(512), 0, stream>>>(x, W_in, b_in, W_rec, b_rec,
                                                 W_out, b_out, out, scratch);
}